// Round 5
// baseline (76.822 us; speedup 1.0000x reference)
//
#include <hip/hip_runtime.h>
#include <math.h>

#define PI_F 3.14159265358979323846f

// ws layout (floats), zeroed by a 25 KB hipMemsetAsync each launch:
//   [0    .. 3136) : sumS  [16 replicas][196 patches]
//   [3136 .. 6272) : sumS2 [16 replicas][196 patches]
// Kernel launch boundary = the grid barrier (R1: cg sync ~50us/sync;
// R2: acquire-spin +8us; R3/R4: boundary = best). Memset is mandatory:
// the harness re-poisons the whole 268 MB ws every iteration.
#define NREP    16
#define S2_OFF  (NREP * 196)
#define NBLK_A  512
#define NBLK_B  512

// Async global->LDS, 16B/lane. LDS dest must be linear in tid within each
// wave (wave-uniform base + lane*16) — all uses below are exactly sx4[tid+C].
#define GLOAD_LDS16(gsrc, ldst)                                              \
    __builtin_amdgcn_global_load_lds(                                        \
        (const __attribute__((address_space(1))) unsigned int*)(gsrc),       \
        (__attribute__((address_space(3))) unsigned int*)(ldst), 16, 0, 0)

// ---------------------------------------------------------------------------
// Kernel A: per-patch partial stats. 512 blocks x 512 thr, 8 images/block.
// Stage via global_load_lds (3 full passes + 32-thread tail), then 392
// threads reduce (patch, image-half) over 4 images each — half the chain
// length of round 4. One atomicAdd pair into replica ((bid<<1)|half)&15:
// relaxed, no fences, ~32 adds/address.
// ---------------------------------------------------------------------------
__global__ __launch_bounds__(512) void k_partial(const float* __restrict__ x,
                                                 float* __restrict__ ws) {
    __shared__ __align__(16) float sx[8 * 784];   // 25088 B
    const int tid = threadIdx.x;
    const float4* x4 = (const float4*)(x + (size_t)blockIdx.x * 8 * 784);
    float4* sx4 = (float4*)sx;
#pragma unroll
    for (int j = 0; j < 3; j++)                   // 1536 of 1568 float4
        GLOAD_LDS16(x4 + tid + j * 512, sx4 + tid + j * 512);
    if (tid < 32) sx4[1536 + tid] = x4[1536 + tid];
    __syncthreads();   // drains vmcnt+lgkmcnt

    if (tid < 392) {
        const int half = (tid >= 196);
        const int p = tid - 196 * half;
        const int r = p / 14;
        const int off = 2 * p + 28 * r;            // even -> 8B aligned
        const float* base = sx + half * (4 * 784) + off;
        float s = 0.f, s2 = 0.f;
#pragma unroll
        for (int j = 0; j < 4; j++) {
            const float* bp = base + j * 784;
            float2 t = *(const float2*)bp;
            float2 u = *(const float2*)(bp + 28);
            s += (t.x + t.y) + (u.x + u.y);
            s2 = fmaf(t.x, t.x, s2); s2 = fmaf(t.y, t.y, s2);
            s2 = fmaf(u.x, u.x, s2); s2 = fmaf(u.y, u.y, s2);
        }
        const int rep = ((blockIdx.x << 1) | half) & (NREP - 1);
        atomicAdd(ws + rep * 196 + p, s);
        atomicAdd(ws + S2_OFF + rep * 196 + p, s2);
    }
}

// ---------------------------------------------------------------------------
// Kernel B: stats finalize (16 replicas; kernel boundary makes A's atomics
// visible to plain loads) + features + GEMV + log_softmax. 512 blocks x
// 512 thr, 1 image/wave. x read directly from global (LLC-hot from A, zero
// reuse -> no LDS staging). W staged via global_load_lds. Circuit reduced
// analytically (RZ phases cancel in |amp|^2; CNOTs permute basis):
// feats = [cos a0, cos a1, cos a0*cos a2, cos a1*cos a3].
// Epilogue: per-wave logits funneled through LDS -> one coalesced 320B
// store per block (was 80 scalar stores).
// ---------------------------------------------------------------------------
__global__ __launch_bounds__(512) void k_main(const float* __restrict__ x,
                                              const float* __restrict__ W,
                                              const float* __restrict__ bias,
                                              const float* __restrict__ ws,
                                              float* __restrict__ out) {
    __shared__ __align__(16) float  sW[7840];     // raw W [10][784]
    __shared__ __align__(8)  float2 sst[196];
    __shared__ __align__(16) float  sout[80];
    __shared__ float sbias[10];

    const int tid = threadIdx.x;
    const float4* W4 = (const float4*)W;
    float4* sW4 = (float4*)sW;
#pragma unroll
    for (int j = 0; j < 3; j++)                   // 1536 of 1960 float4
        GLOAD_LDS16(W4 + tid + j * 512, sW4 + tid + j * 512);
    if (tid < 424) sW4[1536 + tid] = W4[1536 + tid];
    if (tid < 196) {
        float S = 0.f, S2 = 0.f;
#pragma unroll
        for (int rp = 0; rp < NREP; rp++) {        // coalesced 4B rows
            S  += ws[rp * 196 + tid];
            S2 += ws[S2_OFF + rp * 196 + tid];
        }
        const float mean = S * (1.0f / 16384.0f);
        const float var  = fmaxf((S2 - S * mean) * (1.0f / 16383.0f), 0.f);
        sst[tid] = make_float2(mean, PI_F / (sqrtf(var) + 1e-6f));
    }
    if (tid < 10) sbias[tid] = bias[tid];
    __syncthreads();

    const int wave = tid >> 6;
    const int lane = tid & 63;
    const float* img = x + ((size_t)blockIdx.x * 8 + wave) * 784;  // LLC-hot

    float acc[10];
#pragma unroll
    for (int o = 0; o < 10; o++) acc[o] = 0.f;

    // k = 0..2: all 64 lanes live, branchless
#pragma unroll
    for (int k = 0; k < 3; k++) {
        const int p = lane + 64 * k;
        const int r = p / 14;
        const int off = 2 * p + 28 * r;            // even -> 8B aligned
        float2 t = *(const float2*)(img + off);
        float2 u = *(const float2*)(img + off + 28);
        float2 ms = sst[p];
        float c0 = __cosf((t.x - ms.x) * ms.y);
        float c1 = __cosf((t.y - ms.x) * ms.y);
        float f2 = c0 * __cosf((u.x - ms.x) * ms.y);
        float f3 = c1 * __cosf((u.y - ms.x) * ms.y);
        const float* wp = sW + 4 * p;
#pragma unroll
        for (int o = 0; o < 10; o++) {
            float4 w = *(const float4*)(wp + o * 784);
            acc[o] += fmaf(c0, w.x, fmaf(c1, w.y,
                      fmaf(f2, w.z, f3 * w.w)));
        }
    }
    // k = 3 peeled: patches 192..195, lanes 0..3 only
    if (lane < 4) {
        const int p = lane + 192;
        const int r = p / 14;
        const int off = 2 * p + 28 * r;
        float2 t = *(const float2*)(img + off);
        float2 u = *(const float2*)(img + off + 28);
        float2 ms = sst[p];
        float c0 = __cosf((t.x - ms.x) * ms.y);
        float c1 = __cosf((t.y - ms.x) * ms.y);
        float f2 = c0 * __cosf((u.x - ms.x) * ms.y);
        float f3 = c1 * __cosf((u.y - ms.x) * ms.y);
        const float* wp = sW + 4 * p;
#pragma unroll
        for (int o = 0; o < 10; o++) {
            float4 w = *(const float4*)(wp + o * 784);
            acc[o] += fmaf(c0, w.x, fmaf(c1, w.y,
                      fmaf(f2, w.z, f3 * w.w)));
        }
    }

#pragma unroll
    for (int o = 0; o < 10; o++) {
#pragma unroll
        for (int sh = 32; sh > 0; sh >>= 1)
            acc[o] += __shfl_down(acc[o], sh, 64);
    }

    if (lane == 0) {
        float m = -INFINITY;
#pragma unroll
        for (int o = 0; o < 10; o++) { acc[o] += sbias[o]; m = fmaxf(m, acc[o]); }
        float ssum = 0.f;
#pragma unroll
        for (int o = 0; o < 10; o++) ssum += __expf(acc[o] - m);
        const float lse = m + __logf(ssum);
#pragma unroll
        for (int o = 0; o < 10; o++) sout[wave * 10 + o] = acc[o] - lse;
    }
    __syncthreads();
    if (tid < 80)                                   // one coalesced 320B store
        out[(size_t)blockIdx.x * 80 + tid] = sout[tid];
}

extern "C" void kernel_launch(void* const* d_in, const int* in_sizes, int n_in,
                              void* d_out, int out_size, void* d_ws, size_t ws_size,
                              hipStream_t stream) {
    const float* x    = (const float*)d_in[0];
    // d_in[1] = params: provably unused (RZ phases cancel in |amp|^2)
    const float* W    = (const float*)d_in[2];
    const float* bias = (const float*)d_in[3];
    float* ws  = (float*)d_ws;
    float* out = (float*)d_out;

    // zero the 25 KB replica accumulators (graph-capture-safe)
    hipMemsetAsync(d_ws, 0, 2 * NREP * 196 * sizeof(float), stream);
    hipLaunchKernelGGL(k_partial, dim3(NBLK_A), dim3(512), 0, stream, x, ws);
    hipLaunchKernelGGL(k_main,    dim3(NBLK_B), dim3(512), 0, stream,
                       x, W, bias, ws, out);
}